// Round 14
// baseline (314.329 us; speedup 1.0000x reference)
//
#include <hip/hip_runtime.h>
#include <cmath>

// LeWin block: B=8, C=64, H=W=256, ws=8, heads=4, hd=16, hidden=256.
// Kernel P: pack weights bf16 [n][k] (q pre-scaled 0.25) + rel-pos bias table
// Kernel A: 512 thr = 2 windows/block, channel-pair float4 loads + packed b32
//           transpose writes. LN1 + attention (register MFMA chain) -> x1 bf16
// Kernel B: LN2-from-global + FFN (swapped-GEMM1, mt-outer single-d1 to cut VGPR)
//           + late halo + conv -> out. Targets LDS 25600B AND VGPR<=56 -> 6 blocks/CU.
// NOTE: __launch_bounds__ 2nd arg N caps VGPRs at ~256/N (256-thr block); N>=4 spills.
// NOTE: VGPR cliff is INCLUSIVE at 64 (>=64 halves waves/SIMD: R13 measured 64 VGPR
//       -> 43% occupancy despite 6-block LDS). Keep hot kernels at <=56 VGPR.

typedef __attribute__((ext_vector_type(8))) short bf16x8;
typedef __attribute__((ext_vector_type(4))) short s16x4;
typedef __attribute__((ext_vector_type(4))) float f32x4;
typedef __attribute__((ext_vector_type(2))) __bf16 bfv2;
typedef __attribute__((ext_vector_type(4))) __bf16 bfv4;

static __device__ __forceinline__ unsigned short f2bf(float f) {
  return __builtin_bit_cast(unsigned short, (__bf16)f);
}
static __device__ __forceinline__ unsigned f2bf2(float a, float b) {
  bfv2 v; v.x = (__bf16)a; v.y = (__bf16)b;
  return __builtin_bit_cast(unsigned, v);
}
static __device__ __forceinline__ s16x4 f2bf4(f32x4 f) {
  bfv4 v; v.x = (__bf16)f[0]; v.y = (__bf16)f[1]; v.z = (__bf16)f[2]; v.w = (__bf16)f[3];
  return __builtin_bit_cast(s16x4, v);
}
static __device__ __forceinline__ float bf2f(unsigned short u) {
  union { unsigned u; float f; } v; v.u = ((unsigned)u) << 16;
  return v.f;
}
static __device__ __forceinline__ float bf2f_s(short s) { return bf2f((unsigned short)s); }

#if __has_builtin(__builtin_amdgcn_exp2f)
static __device__ __forceinline__ float fast_exp2(float x) { return __builtin_amdgcn_exp2f(x); }
#else
static __device__ __forceinline__ float fast_exp2(float x) { return __expf(x * 0.6931471805599453f); }
#endif

// granule-XOR swizzled addressing for pitch-72 (shorts) token-major bf16 tiles
static __device__ __forceinline__ int swz(int row, int c) {
  return row * 72 + ((((c >> 3) ^ (row >> 3)) & 7) << 3) + (c & 7);
}
static __device__ __forceinline__ int swzg(int row, int g) {
  return row * 72 + (((g ^ (row >> 3)) & 7) << 3);
}

#define MFMA32(a, b, c) __builtin_amdgcn_mfma_f32_16x16x32_bf16(a, b, c, 0, 0, 0)

#if __has_builtin(__builtin_amdgcn_mfma_f32_16x16x16bf16_1k)
static __device__ __forceinline__ f32x4 MFMA16(s16x4 a, s16x4 b, f32x4 c) {
  return __builtin_amdgcn_mfma_f32_16x16x16bf16_1k(a, b, c, 0, 0, 0);
}
#else
static __device__ __forceinline__ f32x4 MFMA16(s16x4 a, s16x4 b, f32x4 c) {
  bf16x8 a8 = (bf16x8){a[0], a[1], a[2], a[3], 0, 0, 0, 0};
  bf16x8 b8 = (bf16x8){b[0], b[1], b[2], b[3], 0, 0, 0, 0};
  return __builtin_amdgcn_mfma_f32_16x16x32_bf16(a8, b8, c, 0, 0, 0);
}
#endif

// ==================== Kernel P: weight packing + bias table ====================
__global__ void pack_weights_kernel(const float* __restrict__ qkv_w,
                                    const float* __restrict__ proj_w,
                                    const float* __restrict__ w1,
                                    const float* __restrict__ w2,
                                    const float* __restrict__ rpb,
                                    unsigned short* __restrict__ qkvt,
                                    unsigned short* __restrict__ projt,
                                    unsigned short* __restrict__ w1t,
                                    unsigned short* __restrict__ w2t,
                                    float* __restrict__ biasg) {
  const int t = blockIdx.x * 256 + threadIdx.x;   // 0..16383
  {
    const int n = t >> 6, k = t & 63;
    if (n < 192) {
      float v = qkv_w[k * 192 + n];
      if (n < 64) v *= 0.25f;               // fold attention scale into q weights
      qkvt[t] = f2bf(v);
    }
    if (n < 64)  projt[t] = f2bf(proj_w[k * 64 + n]);
    w1t[t] = f2bf(w1[k * 256 + n]);
  }
  {
    const int n = t >> 8, k = t & 255;
    w2t[t] = f2bf(w2[k * 64 + n]);
  }
  {
    const int i = (t >> 6) & 63, j = t & 63, h = t >> 12;
    const int ridx = ((i >> 3) - (j >> 3) + 7) * 15 + ((i & 7) - (j & 7) + 7);
    biasg[t] = rpb[ridx * 4 + h];
  }
}

// ==================== Kernel A: 2-window register-chain MFMA attention ====================
__global__ __launch_bounds__(512, 2)
void win_attn_kernel(const float* __restrict__ x,
                     const unsigned short* __restrict__ qkvt,
                     const float* __restrict__ qkv_b,
                     const unsigned short* __restrict__ projt,
                     const float* __restrict__ proj_b,
                     const float* __restrict__ biasg,
                     const float* __restrict__ n1g,
                     const float* __restrict__ n1b,
                     unsigned short* __restrict__ x1b)
{
  __shared__ unsigned short xw[2 * 4608];   // residual bf16 per window, swizzled
  __shared__ unsigned short xn[2 * 4608];   // LN1 -> oh -> store staging, swizzled

  const int tid = threadIdx.x;
  const int bid = blockIdx.x;                       // 0..4095
  const int wid = ((bid & 7) << 9) | (bid >> 3);    // XCD-contiguous
  const int b   = wid >> 9;
  const int wy  = (wid >> 4) & 31;
  const int wxp = wid & 15;                          // window-pair index
  const int y0 = wy << 3, x0 = wxp << 4;

  // ---- load + transpose: channel-pair float4 loads, packed b32 LDS writes ----
  const size_t imgbase = (size_t)b << 22;
#pragma unroll
  for (int i = 0; i < 2; ++i) {
    const int u = i * 512 + tid;                  // 1024 channel-pair x token-quad units
    const int c2 = u >> 5;                        // channel pair 0..31
    const int rem = u & 31;
    const int ty = rem >> 2, txq = rem & 3;       // tx = txq*4 .. +3
    const size_t base = imgbase + (size_t)(y0 + ty) * 256 + x0 + txq * 4;
    const float4 v0 = *(const float4*)&x[base + ((size_t)(2 * c2)     << 16)];
    const float4 v1 = *(const float4*)&x[base + ((size_t)(2 * c2 + 1) << 16)];
    unsigned short* dst = xw + (txq >> 1) * 4608;
    const int tokb = (ty << 3) | ((txq & 1) << 2);
    const int c = 2 * c2;
    *(unsigned*)&dst[swz(tokb + 0, c)] = f2bf2(v0.x, v1.x);
    *(unsigned*)&dst[swz(tokb + 1, c)] = f2bf2(v0.y, v1.y);
    *(unsigned*)&dst[swz(tokb + 2, c)] = f2bf2(v0.z, v1.z);
    *(unsigned*)&dst[swz(tokb + 3, c)] = f2bf2(v0.w, v1.w);
  }
  __syncthreads();

  // ---- LayerNorm1: 128 tokens, 4 lanes each ----
  {
    const int t2 = tid >> 2, q = tid & 3;
    const int wn = t2 >> 6, tok = t2 & 63;
    const unsigned short* xwp = xw + wn * 4608;
    const bf16x8 h0 = *(const bf16x8*)&xwp[swzg(tok, 2 * q)];
    const bf16x8 h1 = *(const bf16x8*)&xwp[swzg(tok, 2 * q + 1)];
    float xv[16], s = 0.f, s2 = 0.f;
#pragma unroll
    for (int j = 0; j < 8; ++j) { xv[j] = bf2f_s(h0[j]); xv[8 + j] = bf2f_s(h1[j]); }
#pragma unroll
    for (int j = 0; j < 16; ++j) { s += xv[j]; s2 += xv[j] * xv[j]; }
    s  += __shfl_xor(s, 1);  s  += __shfl_xor(s, 2);
    s2 += __shfl_xor(s2, 1); s2 += __shfl_xor(s2, 2);
    const float mu   = s * 0.015625f;
    const float rstd = rsqrtf(s2 * 0.015625f - mu * mu + 1e-5f);
#pragma unroll
    for (int j = 0; j < 8; ++j) {
      const int c = q * 16 + j * 2;
      const float a0 = (xv[j * 2 + 0] - mu) * rstd * n1g[c]     + n1b[c];
      const float a1 = (xv[j * 2 + 1] - mu) * rstd * n1g[c + 1] + n1b[c + 1];
      *(unsigned*)&xn[wn * 4608 + swz(tok, c)] = f2bf2(a0, a1);
    }
  }
  __syncthreads();

  const int lane = tid & 63;
  const int w8   = tid >> 6;       // wave 0..7
  const int wn   = w8 >> 2;        // window half
  const int g    = w8 & 3;         // head
  const int lr   = lane & 15;
  const int lg   = lane >> 4;
  const unsigned short* xnp = xn + wn * 4608;
  const unsigned short* xwp = xw + wn * 4608;
  unsigned short*       xnw = xn + wn * 4608;

  bf16x8 afr[4][2];
#pragma unroll
  for (int mt = 0; mt < 4; ++mt)
#pragma unroll
    for (int ks = 0; ks < 2; ++ks)
      afr[mt][ks] = *(const bf16x8*)&xnp[swzg(mt * 16 + lr, ks * 4 + lg)];
  __syncthreads();   // xn dead -> reusable as oh

  // ---- QKV (24 MFMA), biases as C-operand init ----
  const int nbq = g * 16, nbk = 64 + g * 16, nbv = 128 + g * 16;
  f32x4 dqT[4], dkT[4], dv[4];
  {
    const float4 qb = *(const float4*)&qkv_b[nbq + lg * 4];
    const float4 kb = *(const float4*)&qkv_b[nbk + lg * 4];
    const float  vb = qkv_b[nbv + lr];
    const f32x4 qbv = (f32x4){qb.x * 0.25f, qb.y * 0.25f, qb.z * 0.25f, qb.w * 0.25f};
    const f32x4 kbv = (f32x4){kb.x, kb.y, kb.z, kb.w};
    const f32x4 vbv = (f32x4){vb, vb, vb, vb};
#pragma unroll
    for (int u = 0; u < 4; ++u) { dqT[u] = qbv; dkT[u] = kbv; dv[u] = vbv; }
  }
#pragma unroll
  for (int ks = 0; ks < 2; ++ks) {
    const bf16x8 wq = *(const bf16x8*)&qkvt[(nbq + lr) * 64 + ks * 32 + lg * 8];
    const bf16x8 wk = *(const bf16x8*)&qkvt[(nbk + lr) * 64 + ks * 32 + lg * 8];
    const bf16x8 wv = *(const bf16x8*)&qkvt[(nbv + lr) * 64 + ks * 32 + lg * 8];
#pragma unroll
    for (int u = 0; u < 4; ++u) {
      dqT[u] = MFMA32(wq, afr[u][ks], dqT[u]);   // D[d][tok], scale+bias folded
      dkT[u] = MFMA32(wk, afr[u][ks], dkT[u]);
      dv[u]  = MFMA32(afr[u][ks], wv, dv[u]);    // D[tok][d]
    }
  }
  s16x4 qf[4], kf[4], vf[4];
#pragma unroll
  for (int u = 0; u < 4; ++u) { qf[u] = f2bf4(dqT[u]); kf[u] = f2bf4(dkT[u]); vf[u] = f2bf4(dv[u]); }

  // ---- per-nt fused: S^T (4 MFMA) + bias-as-C + no-max softmax + PV (4 MFMA) ----
  f32x4 o[4];
#pragma unroll
  for (int nt = 0; nt < 4; ++nt) {
    f32x4 sv[4];
#pragma unroll
    for (int mt = 0; mt < 4; ++mt) {
      const float4 bb = *(const float4*)&biasg[(g << 12) + (nt * 16 + lr) * 64 + mt * 16 + lg * 4];
      sv[mt] = MFMA16(kf[mt], qf[nt], (f32x4){bb.x, bb.y, bb.z, bb.w});
    }
    float sum = 0.f;
#pragma unroll
    for (int mt = 0; mt < 4; ++mt)
#pragma unroll
      for (int r = 0; r < 4; ++r) { const float e = __expf(sv[mt][r]); sv[mt][r] = e; sum += e; }
    sum += __shfl_xor(sum, 16);
    sum += __shfl_xor(sum, 32);
    const float rs = 1.f / sum;
    o[nt] = (f32x4){0, 0, 0, 0};
#pragma unroll
    for (int mt = 0; mt < 4; ++mt) {
      const s16x4 p = f2bf4(sv[mt] * rs);
      o[nt] = MFMA16(p, vf[mt], o[nt]);
    }
  }
#pragma unroll
  for (int nt = 0; nt < 4; ++nt)
#pragma unroll
    for (int r = 0; r < 4; ++r)
      xnw[swz(nt * 16 + lg * 4 + r, g * 16 + lr)] = f2bf(o[nt][r]);
  __syncthreads();

  // ---- proj (8 MFMA, bias as C) + residual -> staging -> coalesced store ----
  {
    bf16x8 pa2[4][2];
#pragma unroll
    for (int mt = 0; mt < 4; ++mt)
#pragma unroll
      for (int ks = 0; ks < 2; ++ks)
        pa2[mt][ks] = *(const bf16x8*)&xnp[swzg(mt * 16 + lr, ks * 4 + lg)];
    __syncthreads();   // oh reads done; xn free for staging

    const float pbias = proj_b[g * 16 + lr];
    f32x4 d2[4];
#pragma unroll
    for (int mt = 0; mt < 4; ++mt) d2[mt] = (f32x4){pbias, pbias, pbias, pbias};
#pragma unroll
    for (int ks = 0; ks < 2; ++ks) {
      const bf16x8 pb = *(const bf16x8*)&projt[(g * 16 + lr) * 64 + ks * 32 + lg * 8];
#pragma unroll
      for (int mt = 0; mt < 4; ++mt)
        d2[mt] = MFMA32(pa2[mt][ks], pb, d2[mt]);
    }
#pragma unroll
    for (int mt = 0; mt < 4; ++mt)
#pragma unroll
      for (int r = 0; r < 4; ++r) {
        const int tok = mt * 16 + lg * 4 + r;
        const float val = d2[mt][r] + bf2f(xwp[swz(tok, g * 16 + lr)]);
        xnw[swz(tok, g * 16 + lr)] = f2bf(val);
      }
  }
  __syncthreads();

#pragma unroll
  for (int i = 0; i < 2; ++i) {
    const int u = i * 512 + tid;               // 1024 bf16x8 units
    const int tk = u >> 3, gr = u & 7;
    const int wn2 = tk >> 6, tok = tk & 63;
    const bf16x8 v = *(const bf16x8*)&xn[wn2 * 4608 + swzg(tok, gr)];
    *(bf16x8*)&x1b[(((size_t)b * 256 + y0 + (tok >> 3)) * 256 + x0 + wn2 * 8 + (tok & 7)) * 64 + gr * 8] = v;
  }
}

// ==================== Kernel B: LN2-from-global + FFN + late halo + conv ====================
// LDS pool 25600 B (6 blocks/CU), lifetime-exact overlay:
//   xnb  [64][72] bf16 swizzled   [0,    4608)   phases 1-4 (read-only after ph1)
//   hid  [64][128] bf16 swizzled  [4608, 12800)  phases 3-4 (disjoint from xnb)
//   x1h  [100][72] bf16           [0,    7200)   phases 5-6 (xnb+hid dead)
//   d2fb [64][66] bf16 pairs      [7200, 11424)  phases 5-6 (disjoint from x1h)
__global__ __launch_bounds__(256, 2)
void ffn_conv_kernel(const unsigned short* __restrict__ x1b,
                     const float* __restrict__ n2g, const float* __restrict__ n2b,
                     const unsigned short* __restrict__ w1t, const float* __restrict__ b1,
                     const unsigned short* __restrict__ w2t, const float* __restrict__ b2,
                     const float* __restrict__ dww, const float* __restrict__ dwb,
                     float* __restrict__ out)
{
  __shared__ __align__(16) unsigned short pool[12800];   // 25600 B
  unsigned short* xnb  = pool;            // [64][72]
  unsigned short* hid  = pool + 4608;     // [64][128]
  unsigned short* x1h  = pool;            // [100][72]
  unsigned short* d2fb = pool + 7200;     // [64][66]

  const int tid = threadIdx.x;
  const int bid = blockIdx.x;
  const int wid = ((bid & 7) << 10) | (bid >> 3);
  const int b  = wid >> 10;
  const int wy = (wid >> 5) & 31;
  const int wx = wid & 31;
  const int y0 = wy << 3, x0 = wx << 3;

  const int lane = tid & 63;
  const int g    = tid >> 6;
  const int lr   = lane & 15;
  const int lg   = lane >> 4;

  // ---- phase 1: LayerNorm2 from global x1 (coalesced token rows) -> xnb ----
  {
    const int t = tid >> 2, q = tid & 3;
    const size_t tbase = (((size_t)b * 256 + y0 + (t >> 3)) * 256 + x0 + (t & 7)) * 64 + q * 16;
    const bf16x8 h0 = *(const bf16x8*)&x1b[tbase];
    const bf16x8 h1 = *(const bf16x8*)&x1b[tbase + 8];
    float xv[16], s = 0.f, s2 = 0.f;
#pragma unroll
    for (int j = 0; j < 8; ++j) { xv[j] = bf2f_s(h0[j]); xv[8 + j] = bf2f_s(h1[j]); }
#pragma unroll
    for (int j = 0; j < 16; ++j) { s += xv[j]; s2 += xv[j] * xv[j]; }
    s  += __shfl_xor(s, 1);  s  += __shfl_xor(s, 2);
    s2 += __shfl_xor(s2, 1); s2 += __shfl_xor(s2, 2);
    const float mu   = s * 0.015625f;
    const float rstd = rsqrtf(s2 * 0.015625f - mu * mu + 1e-5f);
#pragma unroll
    for (int j = 0; j < 8; ++j) {
      const int c = q * 16 + j * 2;
      const float a0 = (xv[j * 2 + 0] - mu) * rstd * n2g[c]     + n2b[c];
      const float a1 = (xv[j * 2 + 1] - mu) * rstd * n2g[c + 1] + n2b[c + 1];
      *(unsigned*)&xnb[swz(t, c)] = f2bf2(a0, a1);
    }
  }
  __syncthreads();

  // ---- phases 2-4: FFN, two hidden halves. mt-outer single-d1 keeps peak
  //      VGPR low (d1: 16 regs -> 4); aw re-loaded per mt from L2-resident w1t. ----
  const float b2n = b2[g * 16 + lr];
  f32x4 d2[4];
#pragma unroll
  for (int mt = 0; mt < 4; ++mt) d2[mt] = (f32x4){b2n, b2n, b2n, b2n};

#pragma unroll
  for (int half = 0; half < 2; ++half) {
#pragma unroll
    for (int nt = 0; nt < 2; ++nt) {
      const int nb = half * 128 + g * 32 + nt * 16;
      const float4 bb = *(const float4*)&b1[nb + lg * 4];
#pragma unroll
      for (int mt = 0; mt < 4; ++mt) {
        f32x4 d1 = (f32x4){bb.x, bb.y, bb.z, bb.w};
#pragma unroll
        for (int ks = 0; ks < 2; ++ks) {
          const bf16x8 aw = *(const bf16x8*)&w1t[(nb + lr) * 64 + ks * 32 + lg * 8];
          const bf16x8 af = *(const bf16x8*)&xnb[swzg(mt * 16 + lr, ks * 4 + lg)];
          d1 = MFMA32(aw, af, d1);   // lane: (n=nb+lg*4+r, tok=mt*16+lr)
        }
        f32x4 hv;
#pragma unroll
        for (int r = 0; r < 4; ++r) {
          // GELU ~= x * sigmoid(1.702 x) = x / (1 + 2^(-2.4554669 x))
          const float e = fast_exp2(d1[r] * -2.4554669f);
          hv[r] = __fdividef(d1[r], 1.f + e);
        }
        const s16x4 pk = f2bf4(hv);
        const int row  = mt * 16 + lr;
        const int nl   = g * 32 + nt * 16 + lg * 4;
        const int addr = row * 128 + (((nl >> 3) ^ (row & 7)) << 3) + (nl & 7);
        *(s16x4*)&hid[addr] = pk;
      }
    }
    __syncthreads();   // hid half ready

    // GEMM2 (unswapped): A = hid rows (b128, swizzled), B = w2t from global
#pragma unroll
    for (int ks2 = 0; ks2 < 4; ++ks2) {
      const bf16x8 bw = *(const bf16x8*)&w2t[(g * 16 + lr) * 256 + half * 128 + ks2 * 32 + lg * 8];
#pragma unroll
      for (int mt = 0; mt < 4; ++mt) {
        const int row  = mt * 16 + lr;
        const int gran = ks2 * 4 + lg;
        const bf16x8 ah = *(const bf16x8*)&hid[row * 128 + ((gran ^ (row & 7)) << 3)];
        d2[mt] = MFMA32(ah, bw, d2[mt]);
      }
    }
    __syncthreads();   // hid consumed (xnb reads also done) -> x1h/d2fb free
  }

  // ---- phase 5: late halo load + FFN result staging (bf16, pitch 66, plain addr) ----
#pragma unroll
  for (int i = 0; i < 7; ++i) {
    const int u = i * 256 + tid;               // 1600 uint2 units
    if (u < 1600) {
      const int p = u >> 4, c4 = (u & 15) << 2;
      const int py = p / 10, px = p - py * 10;
      const int gy = y0 + py - 1, gx = x0 + px - 1;
      uint2 v = make_uint2(0u, 0u);
      if ((unsigned)gy < 256u && (unsigned)gx < 256u)
        v = *(const uint2*)&x1b[(((size_t)b * 256 + gy) * 256 + gx) * 64 + c4];
      *(uint2*)&x1h[p * 72 + c4] = v;
    }
  }
  {
#pragma unroll
    for (int mt = 0; mt < 4; ++mt)
#pragma unroll
      for (int r = 0; r < 4; ++r)
        d2fb[(mt * 16 + lg * 4 + r) * 66 + g * 16 + lr] = f2bf(d2[mt][r]);
  }
  __syncthreads();

  // ---- phase 6: depthwise conv from x1h + residual + FFN(d2fb) -> out ----
  {
    const int cty = lane >> 3, ctx = lane & 7;
    float cacc[16];
#pragma unroll
    for (int i = 0; i < 16; ++i) cacc[i] = dwb[g * 16 + i];
#pragma unroll
    for (int dy = 0; dy < 3; ++dy)
#pragma unroll
      for (int dx = 0; dx < 3; ++dx) {
        const int p = (cty + dy) * 10 + (ctx + dx);
        const bf16x8 h0 = *(const bf16x8*)&x1h[p * 72 + g * 16];
        const bf16x8 h1 = *(const bf16x8*)&x1h[p * 72 + g * 16 + 8];
        const bool ctr = (dy == 1) && (dx == 1);
#pragma unroll
        for (int i = 0; i < 8; ++i) {
          float w0  = dww[(g * 16 + i) * 9     + dy * 3 + dx];
          float w1_ = dww[(g * 16 + 8 + i) * 9 + dy * 3 + dx];
          if (ctr) { w0 += 1.f; w1_ += 1.f; }   // fold residual into center tap
          cacc[i]     += w0  * bf2f_s(h0[i]);
          cacc[8 + i] += w1_ * bf2f_s(h1[i]);
        }
      }
    const unsigned* fp = (const unsigned*)&d2fb[lane * 66 + g * 16];  // even offset: u32 ok
    const size_t obase = ((size_t)b * 64 + g * 16) * 65536 + (size_t)(y0 + cty) * 256 + (x0 + ctx);
#pragma unroll
    for (int j = 0; j < 8; ++j) {
      const unsigned pw = fp[j];
      out[obase + (size_t)(2 * j)     * 65536] = cacc[2 * j]     + bf2f((unsigned short)(pw & 0xffffu));
      out[obase + (size_t)(2 * j + 1) * 65536] = cacc[2 * j + 1] + bf2f((unsigned short)(pw >> 16));
    }
  }
}

extern "C" void kernel_launch(void* const* d_in, const int* in_sizes, int n_in,
                              void* d_out, int out_size, void* d_ws, size_t ws_size,
                              hipStream_t stream) {
  const float* x      = (const float*)d_in[0];
  const float* qkv_w  = (const float*)d_in[1];
  const float* qkv_b  = (const float*)d_in[2];
  const float* proj_w = (const float*)d_in[3];
  const float* proj_b = (const float*)d_in[4];
  const float* rpb    = (const float*)d_in[5];
  const float* n1g    = (const float*)d_in[6];
  const float* n1b    = (const float*)d_in[7];
  const float* n2g    = (const float*)d_in[8];
  const float* n2b    = (const float*)d_in[9];
  const float* w1     = (const float*)d_in[10];
  const float* b1     = (const float*)d_in[11];
  const float* w2     = (const float*)d_in[12];
  const float* b2     = (const float*)d_in[13];
  const float* dww    = (const float*)d_in[14];
  const float* dwb    = (const float*)d_in[15];
  float* out = (float*)d_out;

  // workspace: x1 bf16 (64 MiB) | packed weights (96 KiB) | bias table (64 KiB)
  unsigned short* x1bf = (unsigned short*)d_ws;
  unsigned short* wbuf = (unsigned short*)((char*)d_ws + 67108864);
  unsigned short* qkvt  = wbuf;            // 192*64
  unsigned short* projt = wbuf + 12288;    // 64*64
  unsigned short* w1t   = wbuf + 16384;    // 256*64
  unsigned short* w2t   = wbuf + 32768;    // 64*256
  float* biasg = (float*)((char*)d_ws + 67108864 + 98304);   // 4*64*64

  pack_weights_kernel<<<64, 256, 0, stream>>>(qkv_w, proj_w, w1, w2, rpb,
                                              qkvt, projt, w1t, w2t, biasg);
  win_attn_kernel<<<4096, 512, 0, stream>>>(x, qkvt, qkv_b, projt, proj_b,
                                            biasg, n1g, n1b, x1bf);
  ffn_conv_kernel<<<8192, 256, 0, stream>>>(x1bf, n2g, n2b, w1t, b1, w2t, b2,
                                            dww, dwb, out);
}

// Round 15
// 311.984 us; speedup vs baseline: 1.0075x; 1.0075x over previous
//
#include <hip/hip_runtime.h>
#include <cmath>

// LeWin block: B=8, C=64, H=W=256, ws=8, heads=4, hd=16, hidden=256.
// Kernel P: pack weights bf16 [n][k] (q pre-scaled 0.25) + rel-pos bias table
// Kernel A: 512 thr = 2 windows/block, channel-pair float4 loads + packed b32
//           transpose writes. LN1 + attention (register MFMA chain) -> x1 bf16
// Kernel B: R11 structure (best measured: VGPR 48): LN2-from-global + FFN
//           (swapped-GEMM1, cached afr, d1[4] per-nt) + late halo + conv.
//           NEW: halo in 4-short-granule XOR layout, pitch 64 -> conv reads go
//           8-way -> ~4-way bank conflict; ds_read_b64 instead of b128.
// NOTE: __launch_bounds__ 2nd arg N caps VGPRs at ~256/N (256-thr block); N>=4 spills.
// NOTE: VGPR cliff is INCLUSIVE at 64 (R13: 64 VGPR -> 43% occ). d2fb-bf16 staging
//       costs ~16 regs vs f32 (R11 48 -> R12 68) - keep f32 d2f staging.

typedef __attribute__((ext_vector_type(8))) short bf16x8;
typedef __attribute__((ext_vector_type(4))) short s16x4;
typedef __attribute__((ext_vector_type(4))) float f32x4;
typedef __attribute__((ext_vector_type(2))) __bf16 bfv2;
typedef __attribute__((ext_vector_type(4))) __bf16 bfv4;

static __device__ __forceinline__ unsigned short f2bf(float f) {
  return __builtin_bit_cast(unsigned short, (__bf16)f);
}
static __device__ __forceinline__ unsigned f2bf2(float a, float b) {
  bfv2 v; v.x = (__bf16)a; v.y = (__bf16)b;
  return __builtin_bit_cast(unsigned, v);
}
static __device__ __forceinline__ s16x4 f2bf4(f32x4 f) {
  bfv4 v; v.x = (__bf16)f[0]; v.y = (__bf16)f[1]; v.z = (__bf16)f[2]; v.w = (__bf16)f[3];
  return __builtin_bit_cast(s16x4, v);
}
static __device__ __forceinline__ float bf2f(unsigned short u) {
  union { unsigned u; float f; } v; v.u = ((unsigned)u) << 16;
  return v.f;
}
static __device__ __forceinline__ float bf2f_s(short s) { return bf2f((unsigned short)s); }

#if __has_builtin(__builtin_amdgcn_exp2f)
static __device__ __forceinline__ float fast_exp2(float x) { return __builtin_amdgcn_exp2f(x); }
#else
static __device__ __forceinline__ float fast_exp2(float x) { return __expf(x * 0.6931471805599453f); }
#endif

// granule-XOR swizzled addressing for pitch-72 (shorts) token-major bf16 tiles
static __device__ __forceinline__ int swz(int row, int c) {
  return row * 72 + ((((c >> 3) ^ (row >> 3)) & 7) << 3) + (c & 7);
}
static __device__ __forceinline__ int swzg(int row, int g) {
  return row * 72 + (((g ^ (row >> 3)) & 7) << 3);
}

#define MFMA32(a, b, c) __builtin_amdgcn_mfma_f32_16x16x32_bf16(a, b, c, 0, 0, 0)

#if __has_builtin(__builtin_amdgcn_mfma_f32_16x16x16bf16_1k)
static __device__ __forceinline__ f32x4 MFMA16(s16x4 a, s16x4 b, f32x4 c) {
  return __builtin_amdgcn_mfma_f32_16x16x16bf16_1k(a, b, c, 0, 0, 0);
}
#else
static __device__ __forceinline__ f32x4 MFMA16(s16x4 a, s16x4 b, f32x4 c) {
  bf16x8 a8 = (bf16x8){a[0], a[1], a[2], a[3], 0, 0, 0, 0};
  bf16x8 b8 = (bf16x8){b[0], b[1], b[2], b[3], 0, 0, 0, 0};
  return __builtin_amdgcn_mfma_f32_16x16x32_bf16(a8, b8, c, 0, 0, 0);
}
#endif

// ==================== Kernel P: weight packing + bias table ====================
__global__ void pack_weights_kernel(const float* __restrict__ qkv_w,
                                    const float* __restrict__ proj_w,
                                    const float* __restrict__ w1,
                                    const float* __restrict__ w2,
                                    const float* __restrict__ rpb,
                                    unsigned short* __restrict__ qkvt,
                                    unsigned short* __restrict__ projt,
                                    unsigned short* __restrict__ w1t,
                                    unsigned short* __restrict__ w2t,
                                    float* __restrict__ biasg) {
  const int t = blockIdx.x * 256 + threadIdx.x;   // 0..16383
  {
    const int n = t >> 6, k = t & 63;
    if (n < 192) {
      float v = qkv_w[k * 192 + n];
      if (n < 64) v *= 0.25f;               // fold attention scale into q weights
      qkvt[t] = f2bf(v);
    }
    if (n < 64)  projt[t] = f2bf(proj_w[k * 64 + n]);
    w1t[t] = f2bf(w1[k * 256 + n]);
  }
  {
    const int n = t >> 8, k = t & 255;
    w2t[t] = f2bf(w2[k * 64 + n]);
  }
  {
    const int i = (t >> 6) & 63, j = t & 63, h = t >> 12;
    const int ridx = ((i >> 3) - (j >> 3) + 7) * 15 + ((i & 7) - (j & 7) + 7);
    biasg[t] = rpb[ridx * 4 + h];
  }
}

// ==================== Kernel A: 2-window register-chain MFMA attention ====================
__global__ __launch_bounds__(512, 2)
void win_attn_kernel(const float* __restrict__ x,
                     const unsigned short* __restrict__ qkvt,
                     const float* __restrict__ qkv_b,
                     const unsigned short* __restrict__ projt,
                     const float* __restrict__ proj_b,
                     const float* __restrict__ biasg,
                     const float* __restrict__ n1g,
                     const float* __restrict__ n1b,
                     unsigned short* __restrict__ x1b)
{
  __shared__ unsigned short xw[2 * 4608];   // residual bf16 per window, swizzled
  __shared__ unsigned short xn[2 * 4608];   // LN1 -> oh -> store staging, swizzled

  const int tid = threadIdx.x;
  const int bid = blockIdx.x;                       // 0..4095
  const int wid = ((bid & 7) << 9) | (bid >> 3);    // XCD-contiguous
  const int b   = wid >> 9;
  const int wy  = (wid >> 4) & 31;
  const int wxp = wid & 15;                          // window-pair index
  const int y0 = wy << 3, x0 = wxp << 4;

  // ---- load + transpose: channel-pair float4 loads, packed b32 LDS writes ----
  const size_t imgbase = (size_t)b << 22;
#pragma unroll
  for (int i = 0; i < 2; ++i) {
    const int u = i * 512 + tid;                  // 1024 channel-pair x token-quad units
    const int c2 = u >> 5;                        // channel pair 0..31
    const int rem = u & 31;
    const int ty = rem >> 2, txq = rem & 3;       // tx = txq*4 .. +3
    const size_t base = imgbase + (size_t)(y0 + ty) * 256 + x0 + txq * 4;
    const float4 v0 = *(const float4*)&x[base + ((size_t)(2 * c2)     << 16)];
    const float4 v1 = *(const float4*)&x[base + ((size_t)(2 * c2 + 1) << 16)];
    unsigned short* dst = xw + (txq >> 1) * 4608;
    const int tokb = (ty << 3) | ((txq & 1) << 2);
    const int c = 2 * c2;
    *(unsigned*)&dst[swz(tokb + 0, c)] = f2bf2(v0.x, v1.x);
    *(unsigned*)&dst[swz(tokb + 1, c)] = f2bf2(v0.y, v1.y);
    *(unsigned*)&dst[swz(tokb + 2, c)] = f2bf2(v0.z, v1.z);
    *(unsigned*)&dst[swz(tokb + 3, c)] = f2bf2(v0.w, v1.w);
  }
  __syncthreads();

  // ---- LayerNorm1: 128 tokens, 4 lanes each ----
  {
    const int t2 = tid >> 2, q = tid & 3;
    const int wn = t2 >> 6, tok = t2 & 63;
    const unsigned short* xwp = xw + wn * 4608;
    const bf16x8 h0 = *(const bf16x8*)&xwp[swzg(tok, 2 * q)];
    const bf16x8 h1 = *(const bf16x8*)&xwp[swzg(tok, 2 * q + 1)];
    float xv[16], s = 0.f, s2 = 0.f;
#pragma unroll
    for (int j = 0; j < 8; ++j) { xv[j] = bf2f_s(h0[j]); xv[8 + j] = bf2f_s(h1[j]); }
#pragma unroll
    for (int j = 0; j < 16; ++j) { s += xv[j]; s2 += xv[j] * xv[j]; }
    s  += __shfl_xor(s, 1);  s  += __shfl_xor(s, 2);
    s2 += __shfl_xor(s2, 1); s2 += __shfl_xor(s2, 2);
    const float mu   = s * 0.015625f;
    const float rstd = rsqrtf(s2 * 0.015625f - mu * mu + 1e-5f);
#pragma unroll
    for (int j = 0; j < 8; ++j) {
      const int c = q * 16 + j * 2;
      const float a0 = (xv[j * 2 + 0] - mu) * rstd * n1g[c]     + n1b[c];
      const float a1 = (xv[j * 2 + 1] - mu) * rstd * n1g[c + 1] + n1b[c + 1];
      *(unsigned*)&xn[wn * 4608 + swz(tok, c)] = f2bf2(a0, a1);
    }
  }
  __syncthreads();

  const int lane = tid & 63;
  const int w8   = tid >> 6;       // wave 0..7
  const int wn   = w8 >> 2;        // window half
  const int g    = w8 & 3;         // head
  const int lr   = lane & 15;
  const int lg   = lane >> 4;
  const unsigned short* xnp = xn + wn * 4608;
  const unsigned short* xwp = xw + wn * 4608;
  unsigned short*       xnw = xn + wn * 4608;

  bf16x8 afr[4][2];
#pragma unroll
  for (int mt = 0; mt < 4; ++mt)
#pragma unroll
    for (int ks = 0; ks < 2; ++ks)
      afr[mt][ks] = *(const bf16x8*)&xnp[swzg(mt * 16 + lr, ks * 4 + lg)];
  __syncthreads();   // xn dead -> reusable as oh

  // ---- QKV (24 MFMA), biases as C-operand init ----
  const int nbq = g * 16, nbk = 64 + g * 16, nbv = 128 + g * 16;
  f32x4 dqT[4], dkT[4], dv[4];
  {
    const float4 qb = *(const float4*)&qkv_b[nbq + lg * 4];
    const float4 kb = *(const float4*)&qkv_b[nbk + lg * 4];
    const float  vb = qkv_b[nbv + lr];
    const f32x4 qbv = (f32x4){qb.x * 0.25f, qb.y * 0.25f, qb.z * 0.25f, qb.w * 0.25f};
    const f32x4 kbv = (f32x4){kb.x, kb.y, kb.z, kb.w};
    const f32x4 vbv = (f32x4){vb, vb, vb, vb};
#pragma unroll
    for (int u = 0; u < 4; ++u) { dqT[u] = qbv; dkT[u] = kbv; dv[u] = vbv; }
  }
#pragma unroll
  for (int ks = 0; ks < 2; ++ks) {
    const bf16x8 wq = *(const bf16x8*)&qkvt[(nbq + lr) * 64 + ks * 32 + lg * 8];
    const bf16x8 wk = *(const bf16x8*)&qkvt[(nbk + lr) * 64 + ks * 32 + lg * 8];
    const bf16x8 wv = *(const bf16x8*)&qkvt[(nbv + lr) * 64 + ks * 32 + lg * 8];
#pragma unroll
    for (int u = 0; u < 4; ++u) {
      dqT[u] = MFMA32(wq, afr[u][ks], dqT[u]);   // D[d][tok], scale+bias folded
      dkT[u] = MFMA32(wk, afr[u][ks], dkT[u]);
      dv[u]  = MFMA32(afr[u][ks], wv, dv[u]);    // D[tok][d]
    }
  }
  s16x4 qf[4], kf[4], vf[4];
#pragma unroll
  for (int u = 0; u < 4; ++u) { qf[u] = f2bf4(dqT[u]); kf[u] = f2bf4(dkT[u]); vf[u] = f2bf4(dv[u]); }

  // ---- per-nt fused: S^T (4 MFMA) + bias-as-C + no-max softmax + PV (4 MFMA) ----
  f32x4 o[4];
#pragma unroll
  for (int nt = 0; nt < 4; ++nt) {
    f32x4 sv[4];
#pragma unroll
    for (int mt = 0; mt < 4; ++mt) {
      const float4 bb = *(const float4*)&biasg[(g << 12) + (nt * 16 + lr) * 64 + mt * 16 + lg * 4];
      sv[mt] = MFMA16(kf[mt], qf[nt], (f32x4){bb.x, bb.y, bb.z, bb.w});
    }
    float sum = 0.f;
#pragma unroll
    for (int mt = 0; mt < 4; ++mt)
#pragma unroll
      for (int r = 0; r < 4; ++r) { const float e = __expf(sv[mt][r]); sv[mt][r] = e; sum += e; }
    sum += __shfl_xor(sum, 16);
    sum += __shfl_xor(sum, 32);
    const float rs = 1.f / sum;
    o[nt] = (f32x4){0, 0, 0, 0};
#pragma unroll
    for (int mt = 0; mt < 4; ++mt) {
      const s16x4 p = f2bf4(sv[mt] * rs);
      o[nt] = MFMA16(p, vf[mt], o[nt]);
    }
  }
#pragma unroll
  for (int nt = 0; nt < 4; ++nt)
#pragma unroll
    for (int r = 0; r < 4; ++r)
      xnw[swz(nt * 16 + lg * 4 + r, g * 16 + lr)] = f2bf(o[nt][r]);
  __syncthreads();

  // ---- proj (8 MFMA, bias as C) + residual -> staging -> coalesced store ----
  {
    bf16x8 pa2[4][2];
#pragma unroll
    for (int mt = 0; mt < 4; ++mt)
#pragma unroll
      for (int ks = 0; ks < 2; ++ks)
        pa2[mt][ks] = *(const bf16x8*)&xnp[swzg(mt * 16 + lr, ks * 4 + lg)];
    __syncthreads();   // oh reads done; xn free for staging

    const float pbias = proj_b[g * 16 + lr];
    f32x4 d2[4];
#pragma unroll
    for (int mt = 0; mt < 4; ++mt) d2[mt] = (f32x4){pbias, pbias, pbias, pbias};
#pragma unroll
    for (int ks = 0; ks < 2; ++ks) {
      const bf16x8 pb = *(const bf16x8*)&projt[(g * 16 + lr) * 64 + ks * 32 + lg * 8];
#pragma unroll
      for (int mt = 0; mt < 4; ++mt)
        d2[mt] = MFMA32(pa2[mt][ks], pb, d2[mt]);
    }
#pragma unroll
    for (int mt = 0; mt < 4; ++mt)
#pragma unroll
      for (int r = 0; r < 4; ++r) {
        const int tok = mt * 16 + lg * 4 + r;
        const float val = d2[mt][r] + bf2f(xwp[swz(tok, g * 16 + lr)]);
        xnw[swz(tok, g * 16 + lr)] = f2bf(val);
      }
  }
  __syncthreads();

#pragma unroll
  for (int i = 0; i < 2; ++i) {
    const int u = i * 512 + tid;               // 1024 bf16x8 units
    const int tk = u >> 3, gr = u & 7;
    const int wn2 = tk >> 6, tok = tk & 63;
    const bf16x8 v = *(const bf16x8*)&xn[wn2 * 4608 + swzg(tok, gr)];
    *(bf16x8*)&x1b[(((size_t)b * 256 + y0 + (tok >> 3)) * 256 + x0 + wn2 * 8 + (tok & 7)) * 64 + gr * 8] = v;
  }
}

// ==================== Kernel B: LN2-from-global + FFN + late halo + conv ====================
// LDS pool 29440 B (5 blocks/CU), lifetime-exact overlay:
//   xnb [64][72] bf16 swizzled        [0,    4608)   phases 1-4
//   hid [64][128] bf16 swizzled       [4608, 12800)  phases 3-4 (disjoint from xnb)
//   x1h [100][64] bf16 granule-XOR    [0,    6400)   phases 5-6 (xnb+hid dead)
//   d2f [64][65] f32 (8320 sh)        [6400, 14720)  phases 5-6 (disjoint from x1h)
__global__ __launch_bounds__(256, 2)
void ffn_conv_kernel(const unsigned short* __restrict__ x1b,
                     const float* __restrict__ n2g, const float* __restrict__ n2b,
                     const unsigned short* __restrict__ w1t, const float* __restrict__ b1,
                     const unsigned short* __restrict__ w2t, const float* __restrict__ b2,
                     const float* __restrict__ dww, const float* __restrict__ dwb,
                     float* __restrict__ out)
{
  __shared__ __align__(16) unsigned short pool[14720];   // 29440 B
  unsigned short* xnb = pool;                    // [64][72]
  unsigned short* hid = pool + 4608;             // [64][128]
  unsigned short* x1h = pool;                    // [100][64] granule-XOR
  float*          d2f = (float*)(pool + 6400);   // [64][65]

  const int tid = threadIdx.x;
  const int bid = blockIdx.x;
  const int wid = ((bid & 7) << 10) | (bid >> 3);
  const int b  = wid >> 10;
  const int wy = (wid >> 5) & 31;
  const int wx = wid & 31;
  const int y0 = wy << 3, x0 = wx << 3;

  const int lane = tid & 63;
  const int g    = tid >> 6;
  const int lr   = lane & 15;
  const int lg   = lane >> 4;

  // ---- phase 1: LayerNorm2 from global x1 (coalesced token rows) -> xnb ----
  {
    const int t = tid >> 2, q = tid & 3;
    const size_t tbase = (((size_t)b * 256 + y0 + (t >> 3)) * 256 + x0 + (t & 7)) * 64 + q * 16;
    const bf16x8 h0 = *(const bf16x8*)&x1b[tbase];
    const bf16x8 h1 = *(const bf16x8*)&x1b[tbase + 8];
    float xv[16], s = 0.f, s2 = 0.f;
#pragma unroll
    for (int j = 0; j < 8; ++j) { xv[j] = bf2f_s(h0[j]); xv[8 + j] = bf2f_s(h1[j]); }
#pragma unroll
    for (int j = 0; j < 16; ++j) { s += xv[j]; s2 += xv[j] * xv[j]; }
    s  += __shfl_xor(s, 1);  s  += __shfl_xor(s, 2);
    s2 += __shfl_xor(s2, 1); s2 += __shfl_xor(s2, 2);
    const float mu   = s * 0.015625f;
    const float rstd = rsqrtf(s2 * 0.015625f - mu * mu + 1e-5f);
#pragma unroll
    for (int j = 0; j < 8; ++j) {
      const int c = q * 16 + j * 2;
      const float a0 = (xv[j * 2 + 0] - mu) * rstd * n2g[c]     + n2b[c];
      const float a1 = (xv[j * 2 + 1] - mu) * rstd * n2g[c + 1] + n2b[c + 1];
      *(unsigned*)&xnb[swz(t, c)] = f2bf2(a0, a1);
    }
  }
  __syncthreads();

  // ---- phase 2: A/B fragments of LN2 output (hid disjoint: no barrier after) ----
  bf16x8 afr[4][2];
#pragma unroll
  for (int mt = 0; mt < 4; ++mt)
#pragma unroll
    for (int ks = 0; ks < 2; ++ks)
      afr[mt][ks] = *(const bf16x8*)&xnb[swzg(mt * 16 + lr, ks * 4 + lg)];

  // ---- phases 3-4: FFN, two hidden halves (R11 structure) ----
  const float b2n = b2[g * 16 + lr];
  f32x4 d2[4];
#pragma unroll
  for (int mt = 0; mt < 4; ++mt) d2[mt] = (f32x4){b2n, b2n, b2n, b2n};

#pragma unroll
  for (int half = 0; half < 2; ++half) {
#pragma unroll
    for (int nt = 0; nt < 2; ++nt) {
      const int nb = half * 128 + g * 32 + nt * 16;
      const float4 bb = *(const float4*)&b1[nb + lg * 4];
      f32x4 d1[4];
#pragma unroll
      for (int mt = 0; mt < 4; ++mt) d1[mt] = (f32x4){bb.x, bb.y, bb.z, bb.w};
#pragma unroll
      for (int ks = 0; ks < 2; ++ks) {
        const bf16x8 aw = *(const bf16x8*)&w1t[(nb + lr) * 64 + ks * 32 + lg * 8];
#pragma unroll
        for (int mt = 0; mt < 4; ++mt)
          d1[mt] = MFMA32(aw, afr[mt][ks], d1[mt]);   // lane: (n=nb+lg*4+r, tok=mt*16+lr)
      }
#pragma unroll
      for (int mt = 0; mt < 4; ++mt) {
        f32x4 hv;
#pragma unroll
        for (int r = 0; r < 4; ++r) {
          // GELU ~= x * sigmoid(1.702 x) = x / (1 + 2^(-2.4554669 x))
          const float e = fast_exp2(d1[mt][r] * -2.4554669f);
          hv[r] = __fdividef(d1[mt][r], 1.f + e);
        }
        const s16x4 pk = f2bf4(hv);
        const int row  = mt * 16 + lr;
        const int nl   = g * 32 + nt * 16 + lg * 4;
        const int addr = row * 128 + (((nl >> 3) ^ (row & 7)) << 3) + (nl & 7);
        *(s16x4*)&hid[addr] = pk;
      }
    }
    __syncthreads();   // hid half ready

    // GEMM2 (unswapped): A = hid rows (b128, swizzled), B = w2t from global
#pragma unroll
    for (int ks2 = 0; ks2 < 4; ++ks2) {
      const bf16x8 bw = *(const bf16x8*)&w2t[(g * 16 + lr) * 256 + half * 128 + ks2 * 32 + lg * 8];
#pragma unroll
      for (int mt = 0; mt < 4; ++mt) {
        const int row  = mt * 16 + lr;
        const int gran = ks2 * 4 + lg;
        const bf16x8 ah = *(const bf16x8*)&hid[row * 128 + ((gran ^ (row & 7)) << 3)];
        d2[mt] = MFMA32(ah, bw, d2[mt]);
      }
    }
    __syncthreads();   // hid consumed (xnb long dead) -> x1h/d2f regions free
  }

  // ---- phase 5: late halo load (granule-XOR layout) + FFN result staging ----
#pragma unroll
  for (int i = 0; i < 7; ++i) {
    const int u = i * 256 + tid;               // 1600 uint2 units
    if (u < 1600) {
      const int p = u >> 4, c4i = u & 15;      // granule index 0..15 (4 shorts each)
      const int py = p / 10, px = p - py * 10;
      const int gy = y0 + py - 1, gx = x0 + px - 1;
      uint2 v = make_uint2(0u, 0u);
      if ((unsigned)gy < 256u && (unsigned)gx < 256u)
        v = *(const uint2*)&x1b[(((size_t)b * 256 + gy) * 256 + gx) * 64 + c4i * 4];
      *(uint2*)&x1h[(p << 6) + ((c4i ^ (p & 15)) << 2)] = v;
    }
  }
  {
#pragma unroll
    for (int mt = 0; mt < 4; ++mt)
#pragma unroll
      for (int r = 0; r < 4; ++r)
        d2f[(mt * 16 + lg * 4 + r) * 65 + g * 16 + lr] = d2[mt][r];
  }
  __syncthreads();

  // ---- phase 6: depthwise conv from x1h (granule-XOR b64 reads) + FFN -> out ----
  {
    const int cty = lane >> 3, ctx = lane & 7;
    float cacc[16];
#pragma unroll
    for (int i = 0; i < 16; ++i) cacc[i] = dwb[g * 16 + i];
#pragma unroll
    for (int dy = 0; dy < 3; ++dy)
#pragma unroll
      for (int dx = 0; dx < 3; ++dx) {
        const int p = (cty + dy) * 10 + (ctx + dx);
        const int base = p << 6, pm = p & 15;
        const bool ctr = (dy == 1) && (dx == 1);
#pragma unroll
        for (int gi2 = 0; gi2 < 4; ++gi2) {
          const s16x4 hv4 = *(const s16x4*)&x1h[base + (((g * 4 + gi2) ^ pm) << 2)];
#pragma unroll
          for (int r = 0; r < 4; ++r) {
            const int c = g * 16 + gi2 * 4 + r;
            float w = dww[c * 9 + dy * 3 + dx];
            if (ctr) w += 1.f;                 // fold residual into center tap
            cacc[gi2 * 4 + r] += w * bf2f_s(hv4[r]);
          }
        }
      }
    const size_t obase = ((size_t)b * 64 + g * 16) * 65536 + (size_t)(y0 + cty) * 256 + (x0 + ctx);
#pragma unroll
    for (int i = 0; i < 16; ++i)
      out[obase + (size_t)i * 65536] = cacc[i] + d2f[lane * 65 + g * 16 + i];
  }
}

extern "C" void kernel_launch(void* const* d_in, const int* in_sizes, int n_in,
                              void* d_out, int out_size, void* d_ws, size_t ws_size,
                              hipStream_t stream) {
  const float* x      = (const float*)d_in[0];
  const float* qkv_w  = (const float*)d_in[1];
  const float* qkv_b  = (const float*)d_in[2];
  const float* proj_w = (const float*)d_in[3];
  const float* proj_b = (const float*)d_in[4];
  const float* rpb    = (const float*)d_in[5];
  const float* n1g    = (const float*)d_in[6];
  const float* n1b    = (const float*)d_in[7];
  const float* n2g    = (const float*)d_in[8];
  const float* n2b    = (const float*)d_in[9];
  const float* w1     = (const float*)d_in[10];
  const float* b1     = (const float*)d_in[11];
  const float* w2     = (const float*)d_in[12];
  const float* b2     = (const float*)d_in[13];
  const float* dww    = (const float*)d_in[14];
  const float* dwb    = (const float*)d_in[15];
  float* out = (float*)d_out;

  // workspace: x1 bf16 (64 MiB) | packed weights (96 KiB) | bias table (64 KiB)
  unsigned short* x1bf = (unsigned short*)d_ws;
  unsigned short* wbuf = (unsigned short*)((char*)d_ws + 67108864);
  unsigned short* qkvt  = wbuf;            // 192*64
  unsigned short* projt = wbuf + 12288;    // 64*64
  unsigned short* w1t   = wbuf + 16384;    // 256*64
  unsigned short* w2t   = wbuf + 32768;    // 64*256
  float* biasg = (float*)((char*)d_ws + 67108864 + 98304);   // 4*64*64

  pack_weights_kernel<<<64, 256, 0, stream>>>(qkv_w, proj_w, w1, w2, rpb,
                                              qkvt, projt, w1t, w2t, biasg);
  win_attn_kernel<<<4096, 512, 0, stream>>>(x, qkvt, qkv_b, projt, proj_b,
                                            biasg, n1g, n1b, x1bf);
  ffn_conv_kernel<<<8192, 256, 0, stream>>>(x1bf, n2g, n2b, w1t, b1, w2t, b2,
                                            dww, dwb, out);
}

// Round 16
// 298.583 us; speedup vs baseline: 1.0527x; 1.0449x over previous
//
#include <hip/hip_runtime.h>
#include <cmath>

// LeWin block: B=8, C=64, H=W=256, ws=8, heads=4, hd=16, hidden=256.
// Kernel P: pack weights bf16 [n][k] (q pre-scaled 0.25) + rel-pos bias table
// Kernel A: 512 thr = 2 windows/block, float4 strip loads. LN1 + attention
//           (register MFMA chain, per-nt fused softmax+PV to cut VGPR) -> x1 bf16
// Kernel B: LN2-from-global + FFN (swapped-GEMM1) + late halo + conv -> out (B,C,H,W)
//           R11 configuration: best measured (total 297.7us; B 183us, VGPR 48).
// NOTE: __launch_bounds__ 2nd arg N caps VGPRs at ~256/N (256-thr block); N>=4 spills.
// NOTE: VGPR cliff is INCLUSIVE at 64; bf16 d2-staging costs +8..16 VGPR vs f32.
// NOTE: usable LDS/CU fits ~4 blocks at 31KB pool (occupancy data suggests ~128KB usable).

typedef __attribute__((ext_vector_type(8))) short bf16x8;
typedef __attribute__((ext_vector_type(4))) short s16x4;
typedef __attribute__((ext_vector_type(4))) float f32x4;
typedef __attribute__((ext_vector_type(2))) __bf16 bfv2;
typedef __attribute__((ext_vector_type(4))) __bf16 bfv4;

static __device__ __forceinline__ unsigned short f2bf(float f) {
  return __builtin_bit_cast(unsigned short, (__bf16)f);
}
static __device__ __forceinline__ unsigned f2bf2(float a, float b) {
  bfv2 v; v.x = (__bf16)a; v.y = (__bf16)b;
  return __builtin_bit_cast(unsigned, v);
}
static __device__ __forceinline__ s16x4 f2bf4(f32x4 f) {
  bfv4 v; v.x = (__bf16)f[0]; v.y = (__bf16)f[1]; v.z = (__bf16)f[2]; v.w = (__bf16)f[3];
  return __builtin_bit_cast(s16x4, v);
}
static __device__ __forceinline__ float bf2f(unsigned short u) {
  union { unsigned u; float f; } v; v.u = ((unsigned)u) << 16;
  return v.f;
}
static __device__ __forceinline__ float bf2f_s(short s) { return bf2f((unsigned short)s); }

#if __has_builtin(__builtin_amdgcn_exp2f)
static __device__ __forceinline__ float fast_exp2(float x) { return __builtin_amdgcn_exp2f(x); }
#else
static __device__ __forceinline__ float fast_exp2(float x) { return __expf(x * 0.6931471805599453f); }
#endif

// granule-XOR swizzled addressing for pitch-72 (shorts) token-major bf16 tiles
static __device__ __forceinline__ int swz(int row, int c) {
  return row * 72 + ((((c >> 3) ^ (row >> 3)) & 7) << 3) + (c & 7);
}
static __device__ __forceinline__ int swzg(int row, int g) {
  return row * 72 + (((g ^ (row >> 3)) & 7) << 3);
}

#define MFMA32(a, b, c) __builtin_amdgcn_mfma_f32_16x16x32_bf16(a, b, c, 0, 0, 0)

#if __has_builtin(__builtin_amdgcn_mfma_f32_16x16x16bf16_1k)
static __device__ __forceinline__ f32x4 MFMA16(s16x4 a, s16x4 b, f32x4 c) {
  return __builtin_amdgcn_mfma_f32_16x16x16bf16_1k(a, b, c, 0, 0, 0);
}
#else
static __device__ __forceinline__ f32x4 MFMA16(s16x4 a, s16x4 b, f32x4 c) {
  bf16x8 a8 = (bf16x8){a[0], a[1], a[2], a[3], 0, 0, 0, 0};
  bf16x8 b8 = (bf16x8){b[0], b[1], b[2], b[3], 0, 0, 0, 0};
  return __builtin_amdgcn_mfma_f32_16x16x32_bf16(a8, b8, c, 0, 0, 0);
}
#endif

// ==================== Kernel P: weight packing + bias table ====================
__global__ void pack_weights_kernel(const float* __restrict__ qkv_w,
                                    const float* __restrict__ proj_w,
                                    const float* __restrict__ w1,
                                    const float* __restrict__ w2,
                                    const float* __restrict__ rpb,
                                    unsigned short* __restrict__ qkvt,
                                    unsigned short* __restrict__ projt,
                                    unsigned short* __restrict__ w1t,
                                    unsigned short* __restrict__ w2t,
                                    float* __restrict__ biasg) {
  const int t = blockIdx.x * 256 + threadIdx.x;   // 0..16383
  {
    const int n = t >> 6, k = t & 63;
    if (n < 192) {
      float v = qkv_w[k * 192 + n];
      if (n < 64) v *= 0.25f;               // fold attention scale into q weights
      qkvt[t] = f2bf(v);
    }
    if (n < 64)  projt[t] = f2bf(proj_w[k * 64 + n]);
    w1t[t] = f2bf(w1[k * 256 + n]);
  }
  {
    const int n = t >> 8, k = t & 255;
    w2t[t] = f2bf(w2[k * 64 + n]);
  }
  {
    const int i = (t >> 6) & 63, j = t & 63, h = t >> 12;
    const int ridx = ((i >> 3) - (j >> 3) + 7) * 15 + ((i & 7) - (j & 7) + 7);
    biasg[t] = rpb[ridx * 4 + h];
  }
}

// ==================== Kernel A: 2-window register-chain MFMA attention ====================
__global__ __launch_bounds__(512, 2)
void win_attn_kernel(const float* __restrict__ x,
                     const unsigned short* __restrict__ qkvt,
                     const float* __restrict__ qkv_b,
                     const unsigned short* __restrict__ projt,
                     const float* __restrict__ proj_b,
                     const float* __restrict__ biasg,
                     const float* __restrict__ n1g,
                     const float* __restrict__ n1b,
                     unsigned short* __restrict__ x1b)
{
  __shared__ unsigned short xw[2 * 4608];   // residual bf16 per window, swizzled
  __shared__ unsigned short xn[2 * 4608];   // LN1 -> oh -> store staging, swizzled

  const int tid = threadIdx.x;
  const int bid = blockIdx.x;                       // 0..4095
  const int wid = ((bid & 7) << 9) | (bid >> 3);    // XCD-contiguous
  const int b   = wid >> 9;
  const int wy  = (wid >> 4) & 31;
  const int wxp = wid & 15;                          // window-pair index
  const int y0 = wy << 3, x0 = wxp << 4;

  // ---- load + transpose: float4 strip loads (full 64B line per 4 lanes) ----
  const size_t imgbase = (size_t)b << 22;
#pragma unroll
  for (int i = 0; i < 4; ++i) {
    const int u = i * 512 + tid;                  // 2048 float4 units
    const int c = u >> 5;
    const int rem = u & 31;
    const int ty = rem >> 2, txq = rem & 3;        // tx = txq*4 .. +3
    const float4 v = *(const float4*)&x[imgbase + ((size_t)c << 16) +
                                        (size_t)(y0 + ty) * 256 + x0 + txq * 4];
    unsigned short* dst = xw + (txq >> 1) * 4608;
    const int tokb = (ty << 3) | ((txq & 1) << 2);
    dst[swz(tokb + 0, c)] = f2bf(v.x);
    dst[swz(tokb + 1, c)] = f2bf(v.y);
    dst[swz(tokb + 2, c)] = f2bf(v.z);
    dst[swz(tokb + 3, c)] = f2bf(v.w);
  }
  __syncthreads();

  // ---- LayerNorm1: 128 tokens, 4 lanes each ----
  {
    const int t2 = tid >> 2, q = tid & 3;
    const int wn = t2 >> 6, tok = t2 & 63;
    const unsigned short* xwp = xw + wn * 4608;
    const bf16x8 h0 = *(const bf16x8*)&xwp[swzg(tok, 2 * q)];
    const bf16x8 h1 = *(const bf16x8*)&xwp[swzg(tok, 2 * q + 1)];
    float xv[16], s = 0.f, s2 = 0.f;
#pragma unroll
    for (int j = 0; j < 8; ++j) { xv[j] = bf2f_s(h0[j]); xv[8 + j] = bf2f_s(h1[j]); }
#pragma unroll
    for (int j = 0; j < 16; ++j) { s += xv[j]; s2 += xv[j] * xv[j]; }
    s  += __shfl_xor(s, 1);  s  += __shfl_xor(s, 2);
    s2 += __shfl_xor(s2, 1); s2 += __shfl_xor(s2, 2);
    const float mu   = s * 0.015625f;
    const float rstd = rsqrtf(s2 * 0.015625f - mu * mu + 1e-5f);
#pragma unroll
    for (int j = 0; j < 8; ++j) {
      const int c = q * 16 + j * 2;
      const float a0 = (xv[j * 2 + 0] - mu) * rstd * n1g[c]     + n1b[c];
      const float a1 = (xv[j * 2 + 1] - mu) * rstd * n1g[c + 1] + n1b[c + 1];
      *(unsigned*)&xn[wn * 4608 + swz(t2 & 63, c)] = f2bf2(a0, a1);
    }
  }
  __syncthreads();

  const int lane = tid & 63;
  const int w8   = tid >> 6;       // wave 0..7
  const int wn   = w8 >> 2;        // window half
  const int g    = w8 & 3;         // head
  const int lr   = lane & 15;
  const int lg   = lane >> 4;
  const unsigned short* xnp = xn + wn * 4608;
  const unsigned short* xwp = xw + wn * 4608;
  unsigned short*       xnw = xn + wn * 4608;

  bf16x8 afr[4][2];
#pragma unroll
  for (int mt = 0; mt < 4; ++mt)
#pragma unroll
    for (int ks = 0; ks < 2; ++ks)
      afr[mt][ks] = *(const bf16x8*)&xnp[swzg(mt * 16 + lr, ks * 4 + lg)];
  __syncthreads();   // xn dead -> reusable as oh

  // ---- QKV (24 MFMA), biases as C-operand init ----
  const int nbq = g * 16, nbk = 64 + g * 16, nbv = 128 + g * 16;
  f32x4 dqT[4], dkT[4], dv[4];
  {
    const float4 qb = *(const float4*)&qkv_b[nbq + lg * 4];
    const float4 kb = *(const float4*)&qkv_b[nbk + lg * 4];
    const float  vb = qkv_b[nbv + lr];
    const f32x4 qbv = (f32x4){qb.x * 0.25f, qb.y * 0.25f, qb.z * 0.25f, qb.w * 0.25f};
    const f32x4 kbv = (f32x4){kb.x, kb.y, kb.z, kb.w};
    const f32x4 vbv = (f32x4){vb, vb, vb, vb};
#pragma unroll
    for (int u = 0; u < 4; ++u) { dqT[u] = qbv; dkT[u] = kbv; dv[u] = vbv; }
  }
#pragma unroll
  for (int ks = 0; ks < 2; ++ks) {
    const bf16x8 wq = *(const bf16x8*)&qkvt[(nbq + lr) * 64 + ks * 32 + lg * 8];
    const bf16x8 wk = *(const bf16x8*)&qkvt[(nbk + lr) * 64 + ks * 32 + lg * 8];
    const bf16x8 wv = *(const bf16x8*)&qkvt[(nbv + lr) * 64 + ks * 32 + lg * 8];
#pragma unroll
    for (int u = 0; u < 4; ++u) {
      dqT[u] = MFMA32(wq, afr[u][ks], dqT[u]);   // D[d][tok], scale+bias folded
      dkT[u] = MFMA32(wk, afr[u][ks], dkT[u]);
      dv[u]  = MFMA32(afr[u][ks], wv, dv[u]);    // D[tok][d]
    }
  }
  s16x4 qf[4], kf[4], vf[4];
#pragma unroll
  for (int u = 0; u < 4; ++u) { qf[u] = f2bf4(dqT[u]); kf[u] = f2bf4(dkT[u]); vf[u] = f2bf4(dv[u]); }

  // ---- per-nt fused: S^T (4 MFMA) + bias-as-C + no-max softmax + PV (4 MFMA) ----
  f32x4 o[4];
#pragma unroll
  for (int nt = 0; nt < 4; ++nt) {
    f32x4 sv[4];
#pragma unroll
    for (int mt = 0; mt < 4; ++mt) {
      const float4 bb = *(const float4*)&biasg[(g << 12) + (nt * 16 + lr) * 64 + mt * 16 + lg * 4];
      sv[mt] = MFMA16(kf[mt], qf[nt], (f32x4){bb.x, bb.y, bb.z, bb.w});
    }
    float sum = 0.f;
#pragma unroll
    for (int mt = 0; mt < 4; ++mt)
#pragma unroll
      for (int r = 0; r < 4; ++r) { const float e = __expf(sv[mt][r]); sv[mt][r] = e; sum += e; }
    sum += __shfl_xor(sum, 16);
    sum += __shfl_xor(sum, 32);
    const float rs = 1.f / sum;
    o[nt] = (f32x4){0, 0, 0, 0};
#pragma unroll
    for (int mt = 0; mt < 4; ++mt) {
      const s16x4 p = f2bf4(sv[mt] * rs);
      o[nt] = MFMA16(p, vf[mt], o[nt]);
    }
  }
#pragma unroll
  for (int nt = 0; nt < 4; ++nt)
#pragma unroll
    for (int r = 0; r < 4; ++r)
      xnw[swz(nt * 16 + lg * 4 + r, g * 16 + lr)] = f2bf(o[nt][r]);
  __syncthreads();

  // ---- proj (8 MFMA, bias as C) + residual -> staging -> coalesced store ----
  {
    bf16x8 pa2[4][2];
#pragma unroll
    for (int mt = 0; mt < 4; ++mt)
#pragma unroll
      for (int ks = 0; ks < 2; ++ks)
        pa2[mt][ks] = *(const bf16x8*)&xnp[swzg(mt * 16 + lr, ks * 4 + lg)];
    __syncthreads();   // oh reads done; xn free for staging

    const float pbias = proj_b[g * 16 + lr];
    f32x4 d2[4];
#pragma unroll
    for (int mt = 0; mt < 4; ++mt) d2[mt] = (f32x4){pbias, pbias, pbias, pbias};
#pragma unroll
    for (int ks = 0; ks < 2; ++ks) {
      const bf16x8 pb = *(const bf16x8*)&projt[(g * 16 + lr) * 64 + ks * 32 + lg * 8];
#pragma unroll
      for (int mt = 0; mt < 4; ++mt)
        d2[mt] = MFMA32(pa2[mt][ks], pb, d2[mt]);
    }
#pragma unroll
    for (int mt = 0; mt < 4; ++mt)
#pragma unroll
      for (int r = 0; r < 4; ++r) {
        const int tok = mt * 16 + lg * 4 + r;
        const float val = d2[mt][r] + bf2f(xwp[swz(tok, g * 16 + lr)]);
        xnw[swz(tok, g * 16 + lr)] = f2bf(val);
      }
  }
  __syncthreads();

#pragma unroll
  for (int i = 0; i < 2; ++i) {
    const int u = i * 512 + tid;               // 1024 bf16x8 units
    const int tk = u >> 3, gr = u & 7;
    const int wn2 = tk >> 6, tok = tk & 63;
    const bf16x8 v = *(const bf16x8*)&xn[wn2 * 4608 + swzg(tok, gr)];
    *(bf16x8*)&x1b[(((size_t)b * 256 + y0 + (tok >> 3)) * 256 + x0 + wn2 * 8 + (tok & 7)) * 64 + gr * 8] = v;
  }
}

// ==================== Kernel B: LN2-from-global + FFN + late halo + conv ====================
// LDS pool 31040 B, lifetime-exact overlay:
//   xnb [64][72] bf16 swizzled    [0,    4608)   phases 1-2
//   hid [64][128] bf16 swizzled   [4608, 12800)  phases 3-4 (disjoint from xnb)
//   x1h [100][72] bf16            [0,    7200)   phases 5-6 (xnb+hid dead)
//   d2f [64][65] f32 (8320 sh)    [7200, 15520)  phases 5-6 (disjoint from x1h)
__global__ __launch_bounds__(256, 2)
void ffn_conv_kernel(const unsigned short* __restrict__ x1b,
                     const float* __restrict__ n2g, const float* __restrict__ n2b,
                     const unsigned short* __restrict__ w1t, const float* __restrict__ b1,
                     const unsigned short* __restrict__ w2t, const float* __restrict__ b2,
                     const float* __restrict__ dww, const float* __restrict__ dwb,
                     float* __restrict__ out)
{
  __shared__ __align__(16) unsigned short pool[15520];   // 31040 B
  unsigned short* xnb = pool;                    // [64][72]
  unsigned short* hid = pool + 4608;             // [64][128]
  unsigned short* x1h = pool;                    // [100][72]
  float*          d2f = (float*)(pool + 7200);   // [64][65]

  const int tid = threadIdx.x;
  const int bid = blockIdx.x;
  const int wid = ((bid & 7) << 10) | (bid >> 3);
  const int b  = wid >> 10;
  const int wy = (wid >> 5) & 31;
  const int wx = wid & 31;
  const int y0 = wy << 3, x0 = wx << 3;

  const int lane = tid & 63;
  const int g    = tid >> 6;
  const int lr   = lane & 15;
  const int lg   = lane >> 4;

  // ---- phase 1: LayerNorm2 from global x1 (coalesced token rows) -> xnb ----
  {
    const int t = tid >> 2, q = tid & 3;
    const size_t tbase = (((size_t)b * 256 + y0 + (t >> 3)) * 256 + x0 + (t & 7)) * 64 + q * 16;
    const bf16x8 h0 = *(const bf16x8*)&x1b[tbase];
    const bf16x8 h1 = *(const bf16x8*)&x1b[tbase + 8];
    float xv[16], s = 0.f, s2 = 0.f;
#pragma unroll
    for (int j = 0; j < 8; ++j) { xv[j] = bf2f_s(h0[j]); xv[8 + j] = bf2f_s(h1[j]); }
#pragma unroll
    for (int j = 0; j < 16; ++j) { s += xv[j]; s2 += xv[j] * xv[j]; }
    s  += __shfl_xor(s, 1);  s  += __shfl_xor(s, 2);
    s2 += __shfl_xor(s2, 1); s2 += __shfl_xor(s2, 2);
    const float mu   = s * 0.015625f;
    const float rstd = rsqrtf(s2 * 0.015625f - mu * mu + 1e-5f);
#pragma unroll
    for (int j = 0; j < 8; ++j) {
      const int c = q * 16 + j * 2;
      const float a0 = (xv[j * 2 + 0] - mu) * rstd * n2g[c]     + n2b[c];
      const float a1 = (xv[j * 2 + 1] - mu) * rstd * n2g[c + 1] + n2b[c + 1];
      *(unsigned*)&xnb[swz(t, c)] = f2bf2(a0, a1);
    }
  }
  __syncthreads();

  // ---- phase 2: A/B fragments of LN2 output (hid disjoint: no barrier after) ----
  bf16x8 afr[4][2];
#pragma unroll
  for (int mt = 0; mt < 4; ++mt)
#pragma unroll
    for (int ks = 0; ks < 2; ++ks)
      afr[mt][ks] = *(const bf16x8*)&xnb[swzg(mt * 16 + lr, ks * 4 + lg)];

  // ---- phases 3-4: FFN, two hidden halves ----
  const float b2n = b2[g * 16 + lr];
  f32x4 d2[4];
#pragma unroll
  for (int mt = 0; mt < 4; ++mt) d2[mt] = (f32x4){b2n, b2n, b2n, b2n};

#pragma unroll
  for (int half = 0; half < 2; ++half) {
#pragma unroll
    for (int nt = 0; nt < 2; ++nt) {
      const int nb = half * 128 + g * 32 + nt * 16;
      const float4 bb = *(const float4*)&b1[nb + lg * 4];
      f32x4 d1[4];
#pragma unroll
      for (int mt = 0; mt < 4; ++mt) d1[mt] = (f32x4){bb.x, bb.y, bb.z, bb.w};
#pragma unroll
      for (int ks = 0; ks < 2; ++ks) {
        const bf16x8 aw = *(const bf16x8*)&w1t[(nb + lr) * 64 + ks * 32 + lg * 8];
#pragma unroll
        for (int mt = 0; mt < 4; ++mt)
          d1[mt] = MFMA32(aw, afr[mt][ks], d1[mt]);   // lane: (n=nb+lg*4+r, tok=mt*16+lr)
      }
#pragma unroll
      for (int mt = 0; mt < 4; ++mt) {
        f32x4 hv;
#pragma unroll
        for (int r = 0; r < 4; ++r) {
          // GELU ~= x * sigmoid(1.702 x) = x / (1 + 2^(-2.4554669 x))
          const float e = fast_exp2(d1[mt][r] * -2.4554669f);
          hv[r] = __fdividef(d1[mt][r], 1.f + e);
        }
        const s16x4 pk = f2bf4(hv);
        const int row  = mt * 16 + lr;
        const int nl   = g * 32 + nt * 16 + lg * 4;
        const int addr = row * 128 + (((nl >> 3) ^ (row & 7)) << 3) + (nl & 7);
        *(s16x4*)&hid[addr] = pk;
      }
    }
    __syncthreads();   // hid half ready

    // GEMM2 (unswapped): A = hid rows (b128, swizzled), B = w2t from global
#pragma unroll
    for (int ks2 = 0; ks2 < 4; ++ks2) {
      const bf16x8 bw = *(const bf16x8*)&w2t[(g * 16 + lr) * 256 + half * 128 + ks2 * 32 + lg * 8];
#pragma unroll
      for (int mt = 0; mt < 4; ++mt) {
        const int row  = mt * 16 + lr;
        const int gran = ks2 * 4 + lg;
        const bf16x8 ah = *(const bf16x8*)&hid[row * 128 + ((gran ^ (row & 7)) << 3)];
        d2[mt] = MFMA32(ah, bw, d2[mt]);
      }
    }
    __syncthreads();   // hid consumed (also: xnb long dead) -> x1h/d2f regions free
  }

  // ---- phase 5: late halo load + FFN result staging ----
#pragma unroll
  for (int i = 0; i < 7; ++i) {
    const int u = i * 256 + tid;               // 1600 uint2 units
    if (u < 1600) {
      const int p = u >> 4, c4 = (u & 15) << 2;
      const int py = p / 10, px = p - py * 10;
      const int gy = y0 + py - 1, gx = x0 + px - 1;
      uint2 v = make_uint2(0u, 0u);
      if ((unsigned)gy < 256u && (unsigned)gx < 256u)
        v = *(const uint2*)&x1b[(((size_t)b * 256 + gy) * 256 + gx) * 64 + c4];
      *(uint2*)&x1h[p * 72 + c4] = v;
    }
  }
  {
#pragma unroll
    for (int mt = 0; mt < 4; ++mt)
#pragma unroll
      for (int r = 0; r < 4; ++r)
        d2f[(mt * 16 + lg * 4 + r) * 65 + g * 16 + lr] = d2[mt][r];
  }
  __syncthreads();

  // ---- phase 6: depthwise conv from x1h + residual + FFN -> out ----
  {
    const int cty = lane >> 3, ctx = lane & 7;
    float cacc[16];
#pragma unroll
    for (int i = 0; i < 16; ++i) cacc[i] = dwb[g * 16 + i];
#pragma unroll
    for (int dy = 0; dy < 3; ++dy)
#pragma unroll
      for (int dx = 0; dx < 3; ++dx) {
        const int p = (cty + dy) * 10 + (ctx + dx);
        const bf16x8 h0 = *(const bf16x8*)&x1h[p * 72 + g * 16];
        const bf16x8 h1 = *(const bf16x8*)&x1h[p * 72 + g * 16 + 8];
        const bool ctr = (dy == 1) && (dx == 1);
#pragma unroll
        for (int i = 0; i < 8; ++i) {
          float w0  = dww[(g * 16 + i) * 9     + dy * 3 + dx];
          float w1_ = dww[(g * 16 + 8 + i) * 9 + dy * 3 + dx];
          if (ctr) { w0 += 1.f; w1_ += 1.f; }   // fold residual into center tap
          cacc[i]     += w0  * bf2f_s(h0[i]);
          cacc[8 + i] += w1_ * bf2f_s(h1[i]);
        }
      }
    const size_t obase = ((size_t)b * 64 + g * 16) * 65536 + (size_t)(y0 + cty) * 256 + (x0 + ctx);
#pragma unroll
    for (int i = 0; i < 16; ++i)
      out[obase + (size_t)i * 65536] = cacc[i] + d2f[lane * 65 + g * 16 + i];
  }
}

extern "C" void kernel_launch(void* const* d_in, const int* in_sizes, int n_in,
                              void* d_out, int out_size, void* d_ws, size_t ws_size,
                              hipStream_t stream) {
  const float* x      = (const float*)d_in[0];
  const float* qkv_w  = (const float*)d_in[1];
  const float* qkv_b  = (const float*)d_in[2];
  const float* proj_w = (const float*)d_in[3];
  const float* proj_b = (const float*)d_in[4];
  const float* rpb    = (const float*)d_in[5];
  const float* n1g    = (const float*)d_in[6];
  const float* n1b    = (const float*)d_in[7];
  const float* n2g    = (const float*)d_in[8];
  const float* n2b    = (const float*)d_in[9];
  const float* w1     = (const float*)d_in[10];
  const float* b1     = (const float*)d_in[11];
  const float* w2     = (const float*)d_in[12];
  const float* b2     = (const float*)d_in[13];
  const float* dww    = (const float*)d_in[14];
  const float* dwb    = (const float*)d_in[15];
  float* out = (float*)d_out;

  // workspace: x1 bf16 (64 MiB) | packed weights (96 KiB) | bias table (64 KiB)
  unsigned short* x1bf = (unsigned short*)d_ws;
  unsigned short* wbuf = (unsigned short*)((char*)d_ws + 67108864);
  unsigned short* qkvt  = wbuf;            // 192*64
  unsigned short* projt = wbuf + 12288;    // 64*64
  unsigned short* w1t   = wbuf + 16384;    // 256*64
  unsigned short* w2t   = wbuf + 32768;    // 64*256
  float* biasg = (float*)((char*)d_ws + 67108864 + 98304);   // 4*64*64

  pack_weights_kernel<<<64, 256, 0, stream>>>(qkv_w, proj_w, w1, w2, rpb,
                                              qkvt, projt, w1t, w2t, biasg);
  win_attn_kernel<<<4096, 512, 0, stream>>>(x, qkvt, qkv_b, projt, proj_b,
                                            biasg, n1g, n1b, x1bf);
  ffn_conv_kernel<<<8192, 256, 0, stream>>>(x1bf, n2g, n2b, w1t, b1, w2t, b2,
                                            dww, dwb, out);
}